// Round 1
// baseline (231.811 us; speedup 1.0000x reference)
//
#include <hip/hip_runtime.h>
#include <hip/hip_bf16.h>

#define B_    32
#define LD_   512
#define LQ_   32
#define E_    300
#define NF_   4
#define D_    304
#define M_    16
#define ALPHA_ 0.9f
#define CIN_  1212          // 3*D + E
#define KP1_  1216          // CIN padded to multiple of 32
#define NCOL_ 1056          // 33 columns * 32 batches
#define NPAD_ 1088          // 17 * 64
#define PPL_  9
#define NEG_N_ 128

typedef short short8 __attribute__((ext_vector_type(8)));
typedef float f32x4 __attribute__((ext_vector_type(4)));

__device__ __forceinline__ unsigned short f2bf(float f) {
    unsigned int x = __float_as_uint(f);
    unsigned int r = (x + 0x7FFFu + ((x >> 16) & 1u)) >> 16;
    return (unsigned short)r;
}
__device__ __forceinline__ float bf2f(unsigned short u) {
    return __uint_as_float(((unsigned int)u) << 16);
}

// ---------------------------------------------------------------------------
// Feature builder: one block per (batch, column). Column 0 = positive sample,
// columns 1..32 = neg candidate j (r = j/9, p = j%9). Output Ft is the GEMM
// B operand, layout [NCOL rows][KP1 k] bf16 (row = CNN input column).
// Rows 0..303 l-part, 304..607 ans-part, 608..911 r-part, 912..1211 query FOFE.
// ---------------------------------------------------------------------------
__global__ __launch_bounds__(256) void build_features(
    const int* __restrict__ doc, const float* __restrict__ doc_f,
    const int* __restrict__ query, const int* __restrict__ target_s,
    const int* __restrict__ target_e, const float* __restrict__ emb,
    const int* __restrict__ rand_length, const int* __restrict__ rand_position,
    unsigned short* __restrict__ Ft)
{
    int bcol = blockIdx.x;
    int b = bcol / 33;
    int col = bcol % 33;
    __shared__ int   s_t[3][16];
    __shared__ float s_w[3][16];
    __shared__ int   s_row[3][16];
    __shared__ int   s_qrow[32];
    __shared__ float s_qw[32];
    int tid = threadIdx.x;

    if (tid < 48) {
        int part = tid >> 4, k = tid & 15;
        int t; float valid;
        if (col == 0) {
            int ts = target_s[b], te = target_e[b];
            int span = te - ts;
            if (part == 0)      { t = ts - 1 - k;  valid = (t >= 0) ? 1.f : 0.f; }
            else if (part == 1) { t = te - k;      valid = (k <= span && t >= 0) ? 1.f : 0.f; }
            else                { t = te + 1 + k;  valid = (t < LD_) ? 1.f : 0.f; }
        } else {
            int j = col - 1;
            int r = j / PPL_, p = j - r * PPL_;
            int rl = rand_length[r];
            int rp = rand_position[r * PPL_ + p];
            if (part == 0)      { t = rp - 1 - k;      valid = (t >= 0) ? 1.f : 0.f; }
            else if (part == 1) { t = rp - k;          valid = (k <= rl && t >= 0) ? 1.f : 0.f; }
            else                { t = rp + rl + 1 + k; valid = (t < LD_) ? 1.f : 0.f; }
        }
        float w = (valid != 0.f) ? powf(ALPHA_, (float)k) : 0.f;
        t = min(max(t, 0), LD_ - 1);
        s_t[part][k] = t;
        s_w[part][k] = w;
        s_row[part][k] = doc[b * LD_ + t];
    }
    if (tid >= 64 && tid < 96) {
        int q = tid - 64;
        s_qrow[q] = query[b * LQ_ + q];
        s_qw[q] = powf(ALPHA_, (float)(LQ_ - 1 - q));
    }
    __syncthreads();

    unsigned short* out = Ft + (size_t)bcol * KP1_;
    for (int c = tid; c < KP1_; c += 256) {
        float acc = 0.f;
        if (c < 912) {
            int part = c / D_;
            int cc = c - part * D_;
            if (cc < E_) {
                for (int i = 0; i < 16; ++i)
                    acc += s_w[part][i] * emb[(size_t)s_row[part][i] * E_ + cc];
            } else {
                int f = cc - E_;
                for (int i = 0; i < 16; ++i)
                    acc += s_w[part][i] * doc_f[(b * LD_ + s_t[part][i]) * NF_ + f];
            }
        } else if (c < CIN_) {
            int ce = c - 912;
            for (int i = 0; i < 32; ++i)
                acc += s_qw[i] * emb[(size_t)s_qrow[i] * E_ + ce];
        }
        out[c] = f2bf(acc);
    }
}

// ---------------------------------------------------------------------------
// Fused fp32 -> bf16 conversion for W1 (K-padded with zeros), W2, W3, W4.
// ---------------------------------------------------------------------------
__global__ __launch_bounds__(256) void convert_all(
    const float* __restrict__ W1, const float* __restrict__ W2,
    const float* __restrict__ W3, const float* __restrict__ W4,
    unsigned short* __restrict__ W1b, unsigned short* __restrict__ W2b,
    unsigned short* __restrict__ W3b, unsigned short* __restrict__ W4b)
{
    const long n1 = 1024L * KP1_;
    const long n2 = 1024L * 1024L;
    const long n4 = 512L * 1024L;
    const long total = n1 + 2 * n2 + n4;
    long stride = (long)gridDim.x * 256L;
    for (long i = (long)blockIdx.x * 256L + threadIdx.x; i < total; i += stride) {
        if (i < n1) {
            long m = i / KP1_; int k = (int)(i - m * KP1_);
            float v = (k < CIN_) ? W1[m * CIN_ + k] : 0.f;
            W1b[i] = f2bf(v);
        } else if (i < n1 + n2) {
            long j = i - n1; W2b[j] = f2bf(W2[j]);
        } else if (i < n1 + 2 * n2) {
            long j = i - n1 - n2; W3b[j] = f2bf(W3[j]);
        } else {
            long j = i - n1 - 2 * n2; W4b[j] = f2bf(W4[j]);
        }
    }
}

// ---------------------------------------------------------------------------
// bf16 MFMA GEMM + ReLU.
// A: [M x K] row-major bf16 (weights).  Bm: [N x K] row-major bf16 (features,
// row = output column).  C: [N x M] row-major bf16.  K multiple of 32.
// Block = 256 threads = 4 waves, 64x64 output tile, each wave a 32x32 quadrant
// as 2x2 of 16x16x32 MFMA.
// ---------------------------------------------------------------------------
__global__ __launch_bounds__(256) void gemm_relu(
    const unsigned short* __restrict__ A,
    const unsigned short* __restrict__ Bm,
    unsigned short* __restrict__ C,
    int M, int K)
{
    __shared__ unsigned short As[64][40];   // +8 pad keeps 16B align, breaks conflicts
    __shared__ unsigned short Bs[64][40];
    int tid = threadIdx.x;
    int m0 = blockIdx.x * 64;
    int n0 = blockIdx.y * 64;
    int w = tid >> 6, lane = tid & 63;
    int wm = (w >> 1) * 32, wn = (w & 1) * 32;
    int lr = tid >> 2;          // staging row 0..63
    int ls = (tid & 3) * 8;     // staging k-offset (8 bf16 = 16B)
    int fr = lane & 15;         // fragment row/col
    int fk = (lane >> 4) * 8;   // fragment k base

    f32x4 acc00 = {0.f, 0.f, 0.f, 0.f};
    f32x4 acc01 = {0.f, 0.f, 0.f, 0.f};
    f32x4 acc10 = {0.f, 0.f, 0.f, 0.f};
    f32x4 acc11 = {0.f, 0.f, 0.f, 0.f};

    for (int k0 = 0; k0 < K; k0 += 32) {
        *(uint4*)(&As[lr][ls]) = *(const uint4*)(A + (size_t)(m0 + lr) * K + k0 + ls);
        *(uint4*)(&Bs[lr][ls]) = *(const uint4*)(Bm + (size_t)(n0 + lr) * K + k0 + ls);
        __syncthreads();
        short8 a0 = *(const short8*)(&As[wm + fr][fk]);
        short8 a1 = *(const short8*)(&As[wm + 16 + fr][fk]);
        short8 b0 = *(const short8*)(&Bs[wn + fr][fk]);
        short8 b1 = *(const short8*)(&Bs[wn + 16 + fr][fk]);
        acc00 = __builtin_amdgcn_mfma_f32_16x16x32_bf16(a0, b0, acc00, 0, 0, 0);
        acc01 = __builtin_amdgcn_mfma_f32_16x16x32_bf16(a0, b1, acc01, 0, 0, 0);
        acc10 = __builtin_amdgcn_mfma_f32_16x16x32_bf16(a1, b0, acc10, 0, 0, 0);
        acc11 = __builtin_amdgcn_mfma_f32_16x16x32_bf16(a1, b1, acc11, 0, 0, 0);
        __syncthreads();
    }

    int rbase = (lane >> 4) * 4;    // C/D: row = (lane>>4)*4 + i
    int cb = lane & 15;             // C/D: col = lane & 15
    #define STORE_TILE(ACC, MT, NT) do {                                   \
        int m = m0 + wm + (MT) * 16 + rbase;                               \
        int n = n0 + wn + (NT) * 16 + cb;                                  \
        ushort4 o;                                                         \
        o.x = f2bf(fmaxf((ACC)[0], 0.f));                                  \
        o.y = f2bf(fmaxf((ACC)[1], 0.f));                                  \
        o.z = f2bf(fmaxf((ACC)[2], 0.f));                                  \
        o.w = f2bf(fmaxf((ACC)[3], 0.f));                                  \
        *(ushort4*)(C + (size_t)n * M + m) = o;                            \
    } while (0)
    STORE_TILE(acc00, 0, 0);
    STORE_TILE(acc01, 0, 1);
    STORE_TILE(acc10, 1, 0);
    STORE_TILE(acc11, 1, 1);
    #undef STORE_TILE
}

// ---------------------------------------------------------------------------
// Final layer: score[col] = sigmoid(W5 . h4[col]).  One wave per column.
// ---------------------------------------------------------------------------
__global__ __launch_bounds__(256) void score_kernel(
    const unsigned short* __restrict__ h4,   // [N x 512] bf16
    const float* __restrict__ W5, float* __restrict__ scores)
{
    int w = threadIdx.x >> 6, lane = threadIdx.x & 63;
    int col = blockIdx.x * 4 + w;
    if (col >= NCOL_) return;
    const unsigned short* row = h4 + (size_t)col * 512 + lane * 8;
    ushort4 v0 = *(const ushort4*)row;
    ushort4 v1 = *(const ushort4*)(row + 4);
    const float* w5 = W5 + lane * 8;
    float z = bf2f(v0.x) * w5[0] + bf2f(v0.y) * w5[1] +
              bf2f(v0.z) * w5[2] + bf2f(v0.w) * w5[3] +
              bf2f(v1.x) * w5[4] + bf2f(v1.y) * w5[5] +
              bf2f(v1.z) * w5[6] + bf2f(v1.w) * w5[7];
    for (int off = 32; off > 0; off >>= 1) z += __shfl_down(z, off, 64);
    if (lane == 0) scores[col] = 1.f / (1.f + expf(-z));
}

// ---------------------------------------------------------------------------
// Loss: sum_b [ 128*(s_pos-1)^2 + sum_j cnt(j)*s_neg(b,j)^2 ]
// ---------------------------------------------------------------------------
__global__ __launch_bounds__(256) void loss_kernel(
    const float* __restrict__ scores, const int* __restrict__ rand_idx,
    float* __restrict__ out)
{
    __shared__ int cnt[32];
    __shared__ float red[256];
    int tid = threadIdx.x;
    if (tid < 32) cnt[tid] = 0;
    __syncthreads();
    if (tid < NEG_N_) atomicAdd(&cnt[rand_idx[tid]], 1);
    __syncthreads();
    float acc = 0.f;
    for (int c = tid; c < NCOL_; c += 256) {
        int c33 = c % 33;
        float s = scores[c];
        if (c33 == 0) { float d = s - 1.f; acc += 128.f * d * d; }
        else          { acc += (float)cnt[c33 - 1] * s * s; }
    }
    red[tid] = acc;
    __syncthreads();
    for (int off = 128; off > 0; off >>= 1) {
        if (tid < off) red[tid] += red[tid + off];
        __syncthreads();
    }
    if (tid == 0) out[0] = red[0];
}

extern "C" void kernel_launch(void* const* d_in, const int* in_sizes, int n_in,
                              void* d_out, int out_size, void* d_ws, size_t ws_size,
                              hipStream_t stream)
{
    const int*   doc        = (const int*)d_in[0];
    const float* doc_f      = (const float*)d_in[1];
    const int*   query      = (const int*)d_in[2];
    const int*   target_s   = (const int*)d_in[3];
    const int*   target_e   = (const int*)d_in[4];
    const float* emb        = (const float*)d_in[7];
    const float* W1         = (const float*)d_in[8];
    const float* W2         = (const float*)d_in[9];
    const float* W3         = (const float*)d_in[10];
    const float* W4         = (const float*)d_in[11];
    const float* W5         = (const float*)d_in[12];
    const int*   rand_length   = (const int*)d_in[13];
    const int*   rand_position = (const int*)d_in[14];
    const int*   rand_idx      = (const int*)d_in[15];

    char* ws = (char*)d_ws;
    size_t off = 0;
    auto alloc = [&](size_t bytes) {
        void* p = ws + off;
        off = (off + bytes + 255) & ~(size_t)255;
        return p;
    };
    unsigned short* W1b = (unsigned short*)alloc((size_t)1024 * KP1_ * 2);
    unsigned short* W2b = (unsigned short*)alloc((size_t)1024 * 1024 * 2);
    unsigned short* W3b = (unsigned short*)alloc((size_t)1024 * 1024 * 2);
    unsigned short* W4b = (unsigned short*)alloc((size_t)512 * 1024 * 2);
    unsigned short* Ft  = (unsigned short*)alloc((size_t)NPAD_ * KP1_ * 2);
    unsigned short* hA  = (unsigned short*)alloc((size_t)NPAD_ * 1024 * 2);
    unsigned short* hB  = (unsigned short*)alloc((size_t)NPAD_ * 1024 * 2);
    float* scores       = (float*)alloc(NCOL_ * sizeof(float));
    (void)ws_size; (void)in_sizes; (void)n_in; (void)out_size;

    // zero the padding rows of Ft (cols 1056..1087 of the GEMM N dim)
    hipMemsetAsync(Ft + (size_t)NCOL_ * KP1_, 0,
                   (size_t)(NPAD_ - NCOL_) * KP1_ * 2, stream);

    convert_all<<<dim3(2048), dim3(256), 0, stream>>>(W1, W2, W3, W4,
                                                      W1b, W2b, W3b, W4b);
    build_features<<<dim3(NCOL_), dim3(256), 0, stream>>>(
        doc, doc_f, query, target_s, target_e, emb,
        rand_length, rand_position, Ft);

    gemm_relu<<<dim3(16, 17), dim3(256), 0, stream>>>(W1b, Ft, hA, 1024, KP1_);
    gemm_relu<<<dim3(16, 17), dim3(256), 0, stream>>>(W2b, hA, hB, 1024, 1024);
    gemm_relu<<<dim3(16, 17), dim3(256), 0, stream>>>(W3b, hB, hA, 1024, 1024);
    gemm_relu<<<dim3(8, 17),  dim3(256), 0, stream>>>(W4b, hA, hB, 512, 1024);

    score_kernel<<<dim3((NCOL_ + 3) / 4), dim3(256), 0, stream>>>(hB, W5, scores);
    loss_kernel<<<dim3(1), dim3(256), 0, stream>>>(scores, rand_idx, (float*)d_out);
}

// Round 2
// 195.073 us; speedup vs baseline: 1.1883x; 1.1883x over previous
//
#include <hip/hip_runtime.h>
#include <hip/hip_bf16.h>

#define B_    32
#define LD_   512
#define LQ_   32
#define E_    300
#define NF_   4
#define D_    304
#define M_    16
#define ALPHA_ 0.9f
#define CIN_  1212          // 3*D + E
#define KP1_  1216          // CIN padded to multiple of 64
#define NCOL_ 1056          // 33 columns * 32 batches
#define NPAD_ 1088          // 17 * 64
#define PPL_  9
#define NEG_N_ 128

typedef short short8 __attribute__((ext_vector_type(8)));
typedef float f32x4 __attribute__((ext_vector_type(4)));

__device__ __forceinline__ unsigned short f2bf(float f) {
    unsigned int x = __float_as_uint(f);
    unsigned int r = (x + 0x7FFFu + ((x >> 16) & 1u)) >> 16;
    return (unsigned short)r;
}
__device__ __forceinline__ float bf2f(unsigned short u) {
    return __uint_as_float(((unsigned int)u) << 16);
}

// ---------------------------------------------------------------------------
// Per-batch query FOFE: qfb[b][0..299] = sum_q alpha^(31-q) emb[query[b,q]].
// Stored as bf16 with row stride 304 (pad zeros). 32 blocks.
// ---------------------------------------------------------------------------
__global__ __launch_bounds__(128) void query_fofe(
    const int* __restrict__ query, const float* __restrict__ emb,
    unsigned short* __restrict__ qfb)
{
    int b = blockIdx.x;
    __shared__ int   rows[32];
    __shared__ float wq[32];
    int tid = threadIdx.x;
    if (tid < 32) {
        rows[tid] = query[b * LQ_ + tid];
        wq[tid] = powf(ALPHA_, (float)(LQ_ - 1 - tid));
    }
    __syncthreads();
    if (tid < 76) {
        int cc = tid * 4;
        float ax = 0.f, ay = 0.f, az = 0.f, aw = 0.f;
        if (cc < 300) {
            for (int i = 0; i < 32; ++i) {
                float4 v = *(const float4*)(emb + (size_t)rows[i] * E_ + cc);
                float wv = wq[i];
                ax += wv * v.x; ay += wv * v.y; az += wv * v.z; aw += wv * v.w;
            }
        }
        ushort4 o; o.x = f2bf(ax); o.y = f2bf(ay); o.z = f2bf(az); o.w = f2bf(aw);
        *(ushort4*)(qfb + (size_t)b * 304 + cc) = o;
    }
}

// ---------------------------------------------------------------------------
// Feature builder: one block per (batch, column). Doc parts gathered with
// float4 loads; query part copied from qfb. Output Ft [NCOL][KP1] bf16.
// ---------------------------------------------------------------------------
__global__ __launch_bounds__(320) void build_features(
    const int* __restrict__ doc, const float* __restrict__ doc_f,
    const int* __restrict__ target_s, const int* __restrict__ target_e,
    const float* __restrict__ emb,
    const int* __restrict__ rand_length, const int* __restrict__ rand_position,
    const unsigned short* __restrict__ qfb,
    unsigned short* __restrict__ Ft)
{
    int bcol = blockIdx.x;
    int b = bcol / 33;
    int col = bcol % 33;
    __shared__ int   s_t[3][16];
    __shared__ float s_w[3][16];
    __shared__ int   s_row[3][16];
    int tid = threadIdx.x;

    if (tid < 48) {
        int part = tid >> 4, k = tid & 15;
        int t; float valid;
        if (col == 0) {
            int ts = target_s[b], te = target_e[b];
            int span = te - ts;
            if (part == 0)      { t = ts - 1 - k;  valid = (t >= 0) ? 1.f : 0.f; }
            else if (part == 1) { t = te - k;      valid = (k <= span && t >= 0) ? 1.f : 0.f; }
            else                { t = te + 1 + k;  valid = (t < LD_) ? 1.f : 0.f; }
        } else {
            int j = col - 1;
            int r = j / PPL_, p = j - r * PPL_;
            int rl = rand_length[r];
            int rp = rand_position[r * PPL_ + p];
            if (part == 0)      { t = rp - 1 - k;      valid = (t >= 0) ? 1.f : 0.f; }
            else if (part == 1) { t = rp - k;          valid = (k <= rl && t >= 0) ? 1.f : 0.f; }
            else                { t = rp + rl + 1 + k; valid = (t < LD_) ? 1.f : 0.f; }
        }
        float w = (valid != 0.f) ? powf(ALPHA_, (float)k) : 0.f;
        t = min(max(t, 0), LD_ - 1);
        s_t[part][k] = t;
        s_w[part][k] = w;
        s_row[part][k] = doc[b * LD_ + t];
    }
    __syncthreads();

    unsigned short* out = Ft + (size_t)bcol * KP1_;
    int g = tid;                       // 0..319; 304 groups of 4 elements
    if (g < 228) {                     // doc parts: 3 * 76 groups
        int part = g / 76;
        int g2 = g - part * 76;
        int cc = g2 * 4;
        float ax = 0.f, ay = 0.f, az = 0.f, aw = 0.f;
        if (cc < 300) {                // emb features
            for (int i = 0; i < 16; ++i) {
                float4 v = *(const float4*)(emb + (size_t)s_row[part][i] * E_ + cc);
                float wv = s_w[part][i];
                ax += wv * v.x; ay += wv * v.y; az += wv * v.z; aw += wv * v.w;
            }
        } else {                       // doc_f features (4 per token)
            for (int i = 0; i < 16; ++i) {
                float4 v = *(const float4*)(doc_f + ((size_t)b * LD_ + s_t[part][i]) * NF_);
                float wv = s_w[part][i];
                ax += wv * v.x; ay += wv * v.y; az += wv * v.z; aw += wv * v.w;
            }
        }
        ushort4 o; o.x = f2bf(ax); o.y = f2bf(ay); o.z = f2bf(az); o.w = f2bf(aw);
        *(ushort4*)(out + 4 * g) = o;
    } else if (g < 303) {              // query part: copy 75 groups from qfb
        *(ushort4*)(out + 4 * g) =
            *(const ushort4*)(qfb + (size_t)b * 304 + (g - 228) * 4);
    } else if (g == 303) {             // K padding 1212..1215
        ushort4 z; z.x = 0; z.y = 0; z.z = 0; z.w = 0;
        *(ushort4*)(out + 4 * g) = z;
    }
}

// ---------------------------------------------------------------------------
// fp32 -> bf16 weight conversion, float4-vectorized. W1 K-padded to KP1.
// ---------------------------------------------------------------------------
__global__ __launch_bounds__(256) void convert_all(
    const float* __restrict__ W1, const float* __restrict__ W2,
    const float* __restrict__ W3, const float* __restrict__ W4,
    unsigned short* __restrict__ W1b, unsigned short* __restrict__ W2b,
    unsigned short* __restrict__ W3b, unsigned short* __restrict__ W4b)
{
    const long n1 = 1024L * KP1_ / 4;      // 311296 groups
    const long n2 = 1024L * 1024L / 4;     // 262144
    const long n4 = 512L * 1024L / 4;      // 131072
    const long total = n1 + 2 * n2 + n4;   // 966656
    long stride = (long)gridDim.x * 256L;
    for (long i = (long)blockIdx.x * 256L + threadIdx.x; i < total; i += stride) {
        ushort4 o;
        if (i < n1) {
            long m = i / 304; int k4 = (int)(i - m * 304);
            if (k4 < 303) {
                float4 v = *(const float4*)(W1 + m * CIN_ + k4 * 4);
                o.x = f2bf(v.x); o.y = f2bf(v.y); o.z = f2bf(v.z); o.w = f2bf(v.w);
            } else { o.x = 0; o.y = 0; o.z = 0; o.w = 0; }
            *(ushort4*)(W1b + i * 4) = o;
        } else if (i < n1 + n2) {
            long j = i - n1;
            float4 v = *(const float4*)(W2 + j * 4);
            o.x = f2bf(v.x); o.y = f2bf(v.y); o.z = f2bf(v.z); o.w = f2bf(v.w);
            *(ushort4*)(W2b + j * 4) = o;
        } else if (i < n1 + 2 * n2) {
            long j = i - n1 - n2;
            float4 v = *(const float4*)(W3 + j * 4);
            o.x = f2bf(v.x); o.y = f2bf(v.y); o.z = f2bf(v.z); o.w = f2bf(v.w);
            *(ushort4*)(W3b + j * 4) = o;
        } else {
            long j = i - n1 - 2 * n2;
            float4 v = *(const float4*)(W4 + j * 4);
            o.x = f2bf(v.x); o.y = f2bf(v.y); o.z = f2bf(v.z); o.w = f2bf(v.w);
            *(ushort4*)(W4b + j * 4) = o;
        }
    }
}

// ---------------------------------------------------------------------------
// bf16 MFMA GEMM + ReLU, double-buffered LDS, BK=64, one barrier/iter.
// A: [M x K] bf16 row-major. Bm: [N x K] bf16 row-major. C: [N x M] bf16.
// 256 threads = 4 waves, 64x64 tile, wave = 32x32 quadrant (2x2 MFMA).
// ---------------------------------------------------------------------------
__global__ __launch_bounds__(256) void gemm_relu(
    const unsigned short* __restrict__ A,
    const unsigned short* __restrict__ Bm,
    unsigned short* __restrict__ C,
    int M, int K)
{
    __shared__ unsigned short As[2][64][72];   // stride 72: 16B-aligned, 2-way banks
    __shared__ unsigned short Bs[2][64][72];
    int tid = threadIdx.x;
    int m0 = blockIdx.x * 64, n0 = blockIdx.y * 64;
    int w = tid >> 6, lane = tid & 63;
    int wm = (w >> 1) * 32, wn = (w & 1) * 32;
    int lr = tid >> 2;            // staging row 0..63
    int ls = (tid & 3) * 16;      // staging k offset (16 shorts = 32B per thread)
    int fr = lane & 15, fk = (lane >> 4) * 8;

    const unsigned short* Arow = A + (size_t)(m0 + lr) * K + ls;
    const unsigned short* Brow = Bm + (size_t)(n0 + lr) * K + ls;

    f32x4 acc00 = {0.f,0.f,0.f,0.f}, acc01 = {0.f,0.f,0.f,0.f};
    f32x4 acc10 = {0.f,0.f,0.f,0.f}, acc11 = {0.f,0.f,0.f,0.f};

    int nk = K >> 6;
    // prologue: tile 0 -> buf 0
    {
        uint4 a0 = *(const uint4*)(Arow);
        uint4 a1 = *(const uint4*)(Arow + 8);
        uint4 b0 = *(const uint4*)(Brow);
        uint4 b1 = *(const uint4*)(Brow + 8);
        *(uint4*)&As[0][lr][ls]     = a0;
        *(uint4*)&As[0][lr][ls + 8] = a1;
        *(uint4*)&Bs[0][lr][ls]     = b0;
        *(uint4*)&Bs[0][lr][ls + 8] = b1;
    }
    __syncthreads();
    int cur = 0;
    for (int i = 0; i < nk; ++i) {
        uint4 na0, na1, nb0, nb1;
        bool more = (i + 1 < nk);
        if (more) {                       // issue next-tile loads BEFORE compute
            const unsigned short* An = Arow + (size_t)(i + 1) * 64;
            const unsigned short* Bn = Brow + (size_t)(i + 1) * 64;
            na0 = *(const uint4*)(An);
            na1 = *(const uint4*)(An + 8);
            nb0 = *(const uint4*)(Bn);
            nb1 = *(const uint4*)(Bn + 8);
        }
        #pragma unroll
        for (int s = 0; s < 2; ++s) {
            short8 fa0 = *(const short8*)&As[cur][wm + fr][s * 32 + fk];
            short8 fa1 = *(const short8*)&As[cur][wm + 16 + fr][s * 32 + fk];
            short8 fb0 = *(const short8*)&Bs[cur][wn + fr][s * 32 + fk];
            short8 fb1 = *(const short8*)&Bs[cur][wn + 16 + fr][s * 32 + fk];
            acc00 = __builtin_amdgcn_mfma_f32_16x16x32_bf16(fa0, fb0, acc00, 0, 0, 0);
            acc01 = __builtin_amdgcn_mfma_f32_16x16x32_bf16(fa0, fb1, acc01, 0, 0, 0);
            acc10 = __builtin_amdgcn_mfma_f32_16x16x32_bf16(fa1, fb0, acc10, 0, 0, 0);
            acc11 = __builtin_amdgcn_mfma_f32_16x16x32_bf16(fa1, fb1, acc11, 0, 0, 0);
        }
        if (more) {
            int nb = cur ^ 1;
            *(uint4*)&As[nb][lr][ls]     = na0;
            *(uint4*)&As[nb][lr][ls + 8] = na1;
            *(uint4*)&Bs[nb][lr][ls]     = nb0;
            *(uint4*)&Bs[nb][lr][ls + 8] = nb1;
        }
        __syncthreads();
        cur ^= 1;
    }

    int rbase = (lane >> 4) * 4;    // C/D: row = (lane>>4)*4 + i
    int cb = lane & 15;             // C/D: col = lane & 15
    #define STORE_TILE(ACC, MT, NT) do {                                   \
        int m = m0 + wm + (MT) * 16 + rbase;                               \
        int n = n0 + wn + (NT) * 16 + cb;                                  \
        ushort4 o;                                                         \
        o.x = f2bf(fmaxf((ACC)[0], 0.f));                                  \
        o.y = f2bf(fmaxf((ACC)[1], 0.f));                                  \
        o.z = f2bf(fmaxf((ACC)[2], 0.f));                                  \
        o.w = f2bf(fmaxf((ACC)[3], 0.f));                                  \
        *(ushort4*)(C + (size_t)n * M + m) = o;                            \
    } while (0)
    STORE_TILE(acc00, 0, 0);
    STORE_TILE(acc01, 0, 1);
    STORE_TILE(acc10, 1, 0);
    STORE_TILE(acc11, 1, 1);
    #undef STORE_TILE
}

// ---------------------------------------------------------------------------
// Fused score + loss: one wave per column; sigmoid(W5.h4); weighted square
// summed via one atomicAdd per block into zeroed d_out.
// ---------------------------------------------------------------------------
__global__ __launch_bounds__(256) void score_loss(
    const unsigned short* __restrict__ h4,   // [N x 512] bf16
    const float* __restrict__ W5, const int* __restrict__ rand_idx,
    float* __restrict__ out)
{
    __shared__ int cnt[32];
    __shared__ float part[4];
    int tid = threadIdx.x;
    if (tid < 32) cnt[tid] = 0;
    __syncthreads();
    if (tid < NEG_N_) atomicAdd(&cnt[rand_idx[tid]], 1);
    __syncthreads();
    int w = tid >> 6, lane = tid & 63;
    int col = blockIdx.x * 4 + w;
    float v = 0.f;
    const unsigned short* row = h4 + (size_t)col * 512 + lane * 8;
    ushort4 v0 = *(const ushort4*)row;
    ushort4 v1 = *(const ushort4*)(row + 4);
    const float* w5 = W5 + lane * 8;
    float z = bf2f(v0.x) * w5[0] + bf2f(v0.y) * w5[1] +
              bf2f(v0.z) * w5[2] + bf2f(v0.w) * w5[3] +
              bf2f(v1.x) * w5[4] + bf2f(v1.y) * w5[5] +
              bf2f(v1.z) * w5[6] + bf2f(v1.w) * w5[7];
    for (int off = 32; off > 0; off >>= 1) z += __shfl_down(z, off, 64);
    if (lane == 0) {
        float s = 1.f / (1.f + expf(-z));
        int c33 = col % 33;
        if (c33 == 0) { float d = s - 1.f; v = 128.f * d * d; }
        else          { v = (float)cnt[c33 - 1] * s * s; }
        part[w] = v;
    }
    __syncthreads();
    if (tid == 0) atomicAdd(out, part[0] + part[1] + part[2] + part[3]);
}

extern "C" void kernel_launch(void* const* d_in, const int* in_sizes, int n_in,
                              void* d_out, int out_size, void* d_ws, size_t ws_size,
                              hipStream_t stream)
{
    const int*   doc        = (const int*)d_in[0];
    const float* doc_f      = (const float*)d_in[1];
    const int*   query      = (const int*)d_in[2];
    const int*   target_s   = (const int*)d_in[3];
    const int*   target_e   = (const int*)d_in[4];
    const float* emb        = (const float*)d_in[7];
    const float* W1         = (const float*)d_in[8];
    const float* W2         = (const float*)d_in[9];
    const float* W3         = (const float*)d_in[10];
    const float* W4         = (const float*)d_in[11];
    const float* W5         = (const float*)d_in[12];
    const int*   rand_length   = (const int*)d_in[13];
    const int*   rand_position = (const int*)d_in[14];
    const int*   rand_idx      = (const int*)d_in[15];

    char* ws = (char*)d_ws;
    size_t off = 0;
    auto alloc = [&](size_t bytes) {
        void* p = ws + off;
        off = (off + bytes + 255) & ~(size_t)255;
        return p;
    };
    unsigned short* W1b = (unsigned short*)alloc((size_t)1024 * KP1_ * 2);
    unsigned short* W2b = (unsigned short*)alloc((size_t)1024 * 1024 * 2);
    unsigned short* W3b = (unsigned short*)alloc((size_t)1024 * 1024 * 2);
    unsigned short* W4b = (unsigned short*)alloc((size_t)512 * 1024 * 2);
    unsigned short* Ft  = (unsigned short*)alloc((size_t)NPAD_ * KP1_ * 2);
    unsigned short* hA  = (unsigned short*)alloc((size_t)NPAD_ * 1024 * 2);
    unsigned short* hB  = (unsigned short*)alloc((size_t)NPAD_ * 1024 * 2);
    unsigned short* qfb = (unsigned short*)alloc((size_t)B_ * 304 * 2);
    float* d_loss = (float*)d_out;
    (void)ws_size; (void)in_sizes; (void)n_in; (void)out_size;

    // zero Ft padding rows (GEMM N rows 1056..1087) and the loss accumulator
    hipMemsetAsync(Ft + (size_t)NCOL_ * KP1_, 0,
                   (size_t)(NPAD_ - NCOL_) * KP1_ * 2, stream);
    hipMemsetAsync(d_loss, 0, sizeof(float), stream);

    convert_all<<<dim3(3776), dim3(256), 0, stream>>>(W1, W2, W3, W4,
                                                      W1b, W2b, W3b, W4b);
    query_fofe<<<dim3(B_), dim3(128), 0, stream>>>(query, emb, qfb);
    build_features<<<dim3(NCOL_), dim3(320), 0, stream>>>(
        doc, doc_f, target_s, target_e, emb,
        rand_length, rand_position, qfb, Ft);

    gemm_relu<<<dim3(16, 17), dim3(256), 0, stream>>>(W1b, Ft, hA, 1024, KP1_);
    gemm_relu<<<dim3(16, 17), dim3(256), 0, stream>>>(W2b, hA, hB, 1024, 1024);
    gemm_relu<<<dim3(16, 17), dim3(256), 0, stream>>>(W3b, hB, hA, 1024, 1024);
    gemm_relu<<<dim3(8, 17),  dim3(256), 0, stream>>>(W4b, hA, hB, 512, 1024);

    score_loss<<<dim3(NCOL_ / 4), dim3(256), 0, stream>>>(hB, W5, rand_idx, d_loss);
}